// Round 21
// baseline (160.529 us; speedup 1.0000x reference)
//
#include <hip/hip_runtime.h>
#include <hip/hip_bf16.h>

typedef __hip_bfloat16 bf16;

#define BATCH 128
#define SEQ   200
#define NUMQ  1000
#define DD    64
#define MM    50
#define MH    25     // m-half
#define CHUNKS 10
#define CLEN   20    // SEQ / CHUNKS
#define RPB   16     // rows per block in K1/K3
#define WSTR  52     // w_buf row stride (50 rounded up to /4)

// r15 config (best: 153.5us) + r12/r13 RFO lesson applied to the SMALL dword
// streams: K1's w/e/a stores and K2's rrow store now go through LDS strips and
// out as float4 (dwordx4 avoids TCC read-for-ownership; dword doesn't).

__device__ __forceinline__ float rdlane(float v, int j) {
    return __uint_as_float(__builtin_amdgcn_readlane(__float_as_uint(v), j));
}

// ---------------- K1: r15 shape + float4 stores via per-wave LDS strip ----------------
__global__ __launch_bounds__(256) void k1_wide(
    const int* __restrict__ q, const int* __restrict__ r,
    const float* __restrict__ k_emb, const float* __restrict__ v_emb,
    const float* __restrict__ Mk,
    const float* __restrict__ We, const float* __restrict__ be,
    const float* __restrict__ Wa, const float* __restrict__ ba,
    float* __restrict__ w_buf, float* __restrict__ e_buf, float* __restrict__ a_buf)
{
    __shared__ float Mk_l[MM][DD + 1];
    __shared__ float We_l[DD][DD + 1];
    __shared__ float Wa_l[DD][DD + 1];
    __shared__ float kv_l[4][128];
    __shared__ float st_l[4][192];       // per-wave: e[0..64) a[64..128) w[128..180)

    const int tid  = threadIdx.x;
    const int w    = tid >> 6;
    const int lane = tid & 63;

    for (int i = tid; i < MM * DD; i += 256) Mk_l[i >> 6][i & 63] = Mk[i];
    for (int i = tid; i < DD * DD; i += 256) {
        We_l[i >> 6][i & 63] = We[i];
        Wa_l[i >> 6][i & 63] = Wa[i];
    }
    __syncthreads();

    const float be_l = be[lane];
    const float ba_l = ba[lane];
    const int row0 = blockIdx.x * RPB;

    for (int it = 0; it < RPB / 4; ++it) {
        const int row = row0 + it * 4 + w;

        int qi = q[row], ri = r[row];
        qi = min(max(qi, 0), NUMQ - 1);
        ri = min(max(ri, 0), 1);
        const int xi = qi + ri * NUMQ;

        kv_l[w][lane]      = k_emb[(size_t)qi * DD + lane];   // same-wave write->read
        kv_l[w][64 + lane] = v_emb[(size_t)xi * DD + lane];

        // softmax over m (lane = m)
        float s = 0.f;
        if (lane < MM) {
            #pragma unroll
            for (int dd = 0; dd < DD; ++dd)
                s = __builtin_fmaf(kv_l[w][dd], Mk_l[lane][dd], s);
        }
        float mx = (lane < MM) ? s : -1e30f;
        #pragma unroll
        for (int off = 32; off >= 1; off >>= 1)
            mx = fmaxf(mx, __shfl_xor(mx, off, 64));
        float ex = (lane < MM) ? expf(s - mx) : 0.f;
        float sm = ex;
        #pragma unroll
        for (int off = 32; off >= 1; off >>= 1)
            sm += __shfl_xor(sm, off, 64);
        const float wm = ex / sm;            // valid lane<50
        if (lane < MM) st_l[w][128 + lane] = wm;
        if (lane >= MM && lane < WSTR) st_l[w][128 + lane] = 0.f;  // pad cols 50,51

        // e, a (lane = d)
        float ea = be_l, aa = ba_l;
        #pragma unroll
        for (int dd = 0; dd < DD; ++dd) {
            const float vb = kv_l[w][64 + dd];
            ea = __builtin_fmaf(vb, We_l[dd][lane], ea);
            aa = __builtin_fmaf(vb, Wa_l[dd][lane], aa);
        }
        st_l[w][lane]      = 1.f / (1.f + expf(-ea));
        st_l[w][64 + lane] = tanhf(aa);

        // same-wave in-order LDS write->read; emit float4 (dwordx4: no RFO)
        if (lane < 16) {
            const float4 v4 = *reinterpret_cast<const float4*>(&st_l[w][4 * lane]);
            *reinterpret_cast<float4*>(&e_buf[(size_t)row * DD + 4 * lane]) = v4;
        } else if (lane < 32) {
            const float4 v4 = *reinterpret_cast<const float4*>(&st_l[w][64 + 4 * (lane - 16)]);
            *reinterpret_cast<float4*>(&a_buf[(size_t)row * DD + 4 * (lane - 16)]) = v4;
        } else if (lane < 45) {              // 13 lanes x 16B = 208B = WSTR floats
            const float4 v4 = *reinterpret_cast<const float4*>(&st_l[w][128 + 4 * (lane - 32)]);
            *reinterpret_cast<float4*>(&w_buf[(size_t)row * WSTR + 4 * (lane - 32)]) = v4;
        }
    }
}

// ---------------- K2: r15 k2_hier + float4 rrow flush (w stride 52) ----------------
__global__ __launch_bounds__(640) void k2_hier(
    const float* __restrict__ Mv0,
    const float* __restrict__ w_buf, const float* __restrict__ e_buf,
    const float* __restrict__ a_buf,
    float* __restrict__ read2_buf, float* __restrict__ out_Mv)
{
    __shared__ float POOL[CHUNKS * MH * DD];   // 62.5 KB
    __shared__ float RB[CHUNKS][4 * DD];       // 10 KB: per-wave 4-step racc strip

    const int blk  = blockIdx.x;
    const int b    = blk >> 1;
    const int h    = blk & 1;
    const int tid  = threadIdx.x;
    const int wv   = tid >> 6;
    const int lane = tid & 63;
    const int t0   = wv * CLEN;
    const int mb   = h * MH;

    const float* wrow = w_buf + (size_t)b * SEQ * WSTR + mb;
    const float* erow = e_buf + (size_t)b * SEQ * DD;
    const float* arow = a_buf + (size_t)b * SEQ * DD;

    float A[MH], B[MH];
    #pragma unroll
    for (int j = 0; j < MH; ++j) { A[j] = 1.f; B[j] = 0.f; }

    float wreg = (lane < MH) ? wrow[(size_t)t0 * WSTR + lane] : 0.f;
    float e_n  = erow[(size_t)t0 * DD + lane];
    float a_n  = arow[(size_t)t0 * DD + lane];

    for (int tt = 0; tt < CLEN; ++tt) {
        const int t = t0 + tt;
        const float e_v = e_n, a_v = a_n, wcur = wreg;
        if (t + 1 < SEQ) {
            wreg = (lane < MH) ? wrow[(size_t)(t + 1) * WSTR + lane] : 0.f;
            e_n  = erow[(size_t)(t + 1) * DD + lane];
            a_n  = arow[(size_t)(t + 1) * DD + lane];
        }
        #pragma unroll
        for (int j = 0; j < MH; ++j) {
            const float wj = rdlane(wcur, j);
            const float f  = __builtin_fmaf(-wj, e_v, 1.f);
            A[j] *= f;
            B[j] = __builtin_fmaf(B[j], f, wj * a_v);
        }
    }

    float* outb = out_Mv + (size_t)b * (SEQ + 1) * MM * DD + (size_t)mb * DD;
    if (wv == 0) {
        #pragma unroll
        for (int j = 0; j < MH; ++j) {
            const float m0v = Mv0[(mb + j) * DD + lane];
            POOL[j * DD + lane] = m0v;
            outb[j * DD + lane] = m0v;
        }
    }
    __syncthreads();

    float Mv[MH];
    for (int w = 0; w < CHUNKS; ++w) {
        if (wv == w) {
            #pragma unroll
            for (int j = 0; j < MH; ++j) {
                Mv[j] = POOL[j * DD + lane];
                POOL[j * DD + lane] = __builtin_fmaf(A[j], Mv[j], B[j]);
            }
        }
        __syncthreads();
    }

    float* rrow = read2_buf + ((size_t)h * BATCH + b) * SEQ * DD;
    float* sp   = POOL + wv * (MH * DD);
    float* rb   = RB[wv];

    wreg = (lane < MH) ? wrow[(size_t)t0 * WSTR + lane] : 0.f;
    e_n  = erow[(size_t)t0 * DD + lane];
    a_n  = arow[(size_t)t0 * DD + lane];

    for (int tt = 0; tt < CLEN; ++tt) {
        const int t = t0 + tt;
        const float e_v = e_n, a_v = a_n, wcur = wreg;
        if (t + 1 < SEQ) {
            wreg = (lane < MH) ? wrow[(size_t)(t + 1) * WSTR + lane] : 0.f;
            e_n  = erow[(size_t)(t + 1) * DD + lane];
            a_n  = arow[(size_t)(t + 1) * DD + lane];
        }
        float racc0 = 0.f, racc1 = 0.f;
        #pragma unroll
        for (int j = 0; j < MH; ++j) {
            const float wj    = rdlane(wcur, j);
            const float m_old = Mv[j];
            if (j & 1) racc1 = __builtin_fmaf(wj, m_old, racc1);
            else       racc0 = __builtin_fmaf(wj, m_old, racc0);
            Mv[j] = __builtin_fmaf(wj, __builtin_fmaf(-e_v, m_old, a_v), m_old);
            sp[j * DD + lane] = Mv[j];
        }
        float* outt = outb + (size_t)(t + 1) * MM * DD;
        #pragma unroll
        for (int k = 0; k < 7; ++k) {
            const int f = lane + 64 * k;
            if (f < MH * DD / 4) {
                const float4 v4 = *reinterpret_cast<const float4*>(&sp[4 * f]);
                *reinterpret_cast<float4*>(&outt[4 * f]) = v4;
            }
        }
        rb[(tt & 3) * DD + lane] = racc0 + racc1;
        if ((tt & 3) == 3) {                 // flush 4 steps as 1KB of float4s (no RFO)
            const float4 v4 = *reinterpret_cast<const float4*>(&rb[4 * lane]);
            *reinterpret_cast<float4*>(&rrow[(size_t)(t0 + tt - 3) * DD + 4 * lane]) = v4;
        }
    }
}

// ---------------- K3: r15 k3_wide (proven) ----------------
__global__ __launch_bounds__(256) void k3_wide(
    const int* __restrict__ q,
    const float* __restrict__ k_emb,
    const float* __restrict__ read2_buf,
    const float* __restrict__ Wf, const float* __restrict__ bfb,
    const float* __restrict__ Wp, const float* __restrict__ bp,
    float* __restrict__ out_p)
{
    __shared__ float Wf_l[2 * DD][DD + 1];
    __shared__ float rk[4][128];

    const int tid  = threadIdx.x;
    const int w    = tid >> 6;
    const int lane = tid & 63;

    for (int i = tid; i < 2 * DD * DD; i += 256)
        Wf_l[i >> 6][i & 63] = Wf[i];
    __syncthreads();

    const float bf_l = bfb[lane];
    const float wp_l = Wp[lane];
    const float bp0  = bp[0];
    const int row0 = blockIdx.x * RPB;

    const float* rd0 = read2_buf;
    const float* rd1 = read2_buf + (size_t)BATCH * SEQ * DD;

    for (int it = 0; it < RPB / 4; ++it) {
        const int row = row0 + it * 4 + w;

        int qi = q[row];
        qi = min(max(qi, 0), NUMQ - 1);
        rk[w][lane]      = rd0[(size_t)row * DD + lane] + rd1[(size_t)row * DD + lane];
        rk[w][64 + lane] = k_emb[(size_t)qi * DD + lane];

        float acc = bf_l;
        #pragma unroll
        for (int i = 0; i < 2 * DD; ++i)
            acc = __builtin_fmaf(rk[w][i], Wf_l[i][lane], acc);
        const float f = tanhf(acc);

        float pv = f * wp_l;
        #pragma unroll
        for (int off = 32; off >= 1; off >>= 1)
            pv += __shfl_xor(pv, off, 64);
        if (lane == 0)
            out_p[row] = 1.f / (1.f + expf(-(pv + bp0)));
    }
}

// ---------------- Last-resort fallback: round-5 fused single kernel (proven, ws-free) ----------------
__global__ __launch_bounds__(640) void dkvmn_fused(
    const int* q_, const int* r_,
    const float* k_emb, const float* v_emb, const float* Mk, const float* Mv0,
    const float* We, const float* be, const float* Wa, const float* ba,
    const float* Wf, const float* bfb, const float* Wp, const float* bp,
    float* out_p, float* out_Mv)
{
    __shared__ float Mk_l[MM][DD + 1];
    __shared__ bf16  ring[SEQ][DD];
    __shared__ int   q_row[SEQ], x_row[SEQ];
    __shared__ float kbuf[DD], vbuf[DD], vbuf2[DD];
    __shared__ float wst[MM], est[DD], ast[DD];
    __shared__ float partial[640];
    __shared__ float bias_e[DD], bias_a[DD];

    const int b    = blockIdx.x;
    const int tid  = threadIdx.x;
    const int wv   = tid >> 6;
    const int lane = tid & 63;

    for (int t = tid; t < SEQ; t += 640) {
        int qi = q_[b * SEQ + t], ri = r_[b * SEQ + t];
        qi = min(max(qi, 0), NUMQ - 1); ri = min(max(ri, 0), 1);
        q_row[t] = qi; x_row[t] = qi + ri * NUMQ;
    }
    for (int i = tid; i < MM * DD; i += 640) Mk_l[i >> 6][i & 63] = Mk[i];
    if (tid < DD) { bias_e[tid] = be[tid]; bias_a[tid] = ba[tid]; }

    const int d  = lane;
    const int m0 = wv * 5;
    float* outb = out_Mv + (size_t)b * (SEQ + 1) * MM * DD;
    float Mv[5];
    #pragma unroll
    for (int j = 0; j < 5; ++j) {
        Mv[j] = Mv0[(m0 + j) * DD + d];
        outb[(m0 + j) * DD + d] = Mv[j];
    }
    __syncthreads();

    float kf_n = 0.f, vf_n = 0.f, vf2_n = 0.f;
    if (wv == 0) kf_n  = k_emb[(size_t)q_row[0] * DD + lane];
    if (wv == 1) vf_n  = v_emb[(size_t)x_row[0] * DD + lane];
    if (wv == 2) vf2_n = v_emb[(size_t)x_row[0] * DD + lane];

    for (int t = 0; t < SEQ; ++t) {
        if (wv == 0) {
            kbuf[lane] = kf_n;
            if (t + 1 < SEQ) kf_n = k_emb[(size_t)q_row[t + 1] * DD + lane];
            float s = 0.f;
            if (lane < MM) {
                #pragma unroll
                for (int dd = 0; dd < DD; ++dd) s += kbuf[dd] * Mk_l[lane][dd];
            }
            float mx = (lane < MM) ? s : -1e30f;
            #pragma unroll
            for (int off = 32; off >= 1; off >>= 1) mx = fmaxf(mx, __shfl_xor(mx, off, 64));
            float ex = (lane < MM) ? expf(s - mx) : 0.f;
            float sm = ex;
            #pragma unroll
            for (int off = 32; off >= 1; off >>= 1) sm += __shfl_xor(sm, off, 64);
            if (lane < MM) wst[lane] = ex / sm;
        } else if (wv == 1) {
            vbuf[lane] = vf_n;
            if (t + 1 < SEQ) vf_n = v_emb[(size_t)x_row[t + 1] * DD + lane];
            float acc = bias_e[lane];
            #pragma unroll
            for (int dd = 0; dd < DD; ++dd) acc += vbuf[dd] * We[dd * DD + lane];
            est[lane] = 1.f / (1.f + expf(-acc));
        } else if (wv == 2) {
            vbuf2[lane] = vf2_n;
            if (t + 1 < SEQ) vf2_n = v_emb[(size_t)x_row[t + 1] * DD + lane];
            float acc = bias_a[lane];
            #pragma unroll
            for (int dd = 0; dd < DD; ++dd) acc += vbuf2[dd] * Wa[dd * DD + lane];
            ast[lane] = tanhf(acc);
        }
        __syncthreads();

        const float e_v = est[d];
        const float a_v = ast[d];
        float racc = 0.f;
        float* outt = outb + (size_t)(t + 1) * MM * DD;
        #pragma unroll
        for (int j = 0; j < 5; ++j) {
            const float wvv = wst[m0 + j];
            racc += wvv * Mv[j];
            Mv[j] = __builtin_fmaf(wvv, a_v - e_v * Mv[j], Mv[j]);
            outt[(m0 + j) * DD + d] = Mv[j];
        }
        partial[tid] = racc;
        __syncthreads();

        if (tid < DD) {
            float rr = 0.f;
            #pragma unroll
            for (int g = 0; g < 10; ++g) rr += partial[g * 64 + tid];
            ring[t][tid] = (bf16)rr;
        }
    }
    __syncthreads();

    for (int t = wv; t < SEQ; t += 10) {
        const int qi = q_row[t];
        const float kreg = k_emb[(size_t)qi * DD + lane];
        float acc = bfb[lane];
        #pragma unroll
        for (int i = 0; i < DD; ++i) acc += (float)ring[t][i] * Wf[i * DD + lane];
        #pragma unroll
        for (int i = 0; i < DD; ++i) acc += __shfl(kreg, i, 64) * Wf[(DD + i) * DD + lane];
        const float f = tanhf(acc);
        float pv = f * Wp[lane];
        #pragma unroll
        for (int off = 32; off >= 1; off >>= 1) pv += __shfl_xor(pv, off, 64);
        if (lane == 0)
            out_p[(size_t)b * SEQ + t] = 1.f / (1.f + expf(-(pv + bp[0])));
    }
}

extern "C" void kernel_launch(void* const* d_in, const int* in_sizes, int n_in,
                              void* d_out, int out_size, void* d_ws, size_t ws_size,
                              hipStream_t stream) {
    const int*   q     = (const int*)  d_in[0];
    const int*   r     = (const int*)  d_in[1];
    const float* k_emb = (const float*)d_in[4];
    const float* v_emb = (const float*)d_in[5];
    const float* Mk    = (const float*)d_in[6];
    const float* Mv0   = (const float*)d_in[7];
    const float* We    = (const float*)d_in[8];
    const float* be    = (const float*)d_in[9];
    const float* Wa    = (const float*)d_in[10];
    const float* ba    = (const float*)d_in[11];
    const float* Wf    = (const float*)d_in[12];
    const float* bfb   = (const float*)d_in[13];
    const float* Wp    = (const float*)d_in[14];
    const float* bp    = (const float*)d_in[15];

    float* out_p  = (float*)d_out;                 // [128,200]
    float* out_Mv = (float*)d_out + BATCH * SEQ;   // [128,201,50,64]

    const size_t N_W  = (size_t)BATCH * SEQ * WSTR;    // w (stride 52)
    const size_t N_D  = (size_t)BATCH * SEQ * DD;      // e / a / read-half
    const size_t WS_NEEDED = (N_W + 4 * N_D) * sizeof(float);   // ~31.5 MB

    const int rows = BATCH * SEQ;

    if (ws_size >= WS_NEEDED) {
        float* w_buf     = (float*)d_ws;           // [B,SEQ,52]
        float* e_buf     = w_buf + N_W;            // [B,SEQ,64]
        float* a_buf     = e_buf + N_D;            // [B,SEQ,64]
        float* read2_buf = a_buf + N_D;            // [2,B,SEQ,64]

        hipLaunchKernelGGL(k1_wide, dim3(rows / RPB), dim3(256), 0, stream,
                           q, r, k_emb, v_emb, Mk, We, be, Wa, ba,
                           w_buf, e_buf, a_buf);
        hipLaunchKernelGGL(k2_hier, dim3(BATCH * 2), dim3(640), 0, stream,
                           Mv0, w_buf, e_buf, a_buf, read2_buf, out_Mv);
        hipLaunchKernelGGL(k3_wide, dim3(rows / RPB), dim3(256), 0, stream,
                           q, k_emb, read2_buf, Wf, bfb, Wp, bp, out_p);
    } else {
        hipLaunchKernelGGL(dkvmn_fused, dim3(BATCH), dim3(640), 0, stream,
                           q, r, k_emb, v_emb, Mk, Mv0, We, be, Wa, ba,
                           Wf, bfb, Wp, bp, out_p, out_Mv);
    }
}